// Round 6
// baseline (295.513 us; speedup 1.0000x reference)
//
#include <hip/hip_runtime.h>
#include <hip/hip_bf16.h>
#include <math.h>

#define HIDDEN 128
#define NNODES 50000
#define NEDGES 600000
#define EPS 1e-5f
#define SCAN_CHUNK 1024
#define NSCAN_BLOCKS ((NNODES + SCAN_CHUNK - 1) / SCAN_CHUNK)  // 49
#define MPAD 50048  // 782 * 64
#define NTILES (MPAD / 16)  // 3128

// phase0 block ranges
#define P0_W6T_END   384
#define P0_BV_END    387
#define P0_WUT_END   515
#define P0_XB_END    (515 + 6256)            // MPAD*128/4/256 = 6256 blocks
#define P0_HIST_END  (P0_XB_END + 2344)      // (NEDGES+255)/256 = 2344 blocks

// Workspace layout (bytes), all 16B-aligned. ABb is FP8 (1B/elem).
#define OFF_W6T  ((size_t)0)            // 768*128*2   = 196,608
#define OFF_BV   ((size_t)196608)       // 768*4       = 3,072   -> 199,680
#define OFF_WUT  ((size_t)199680)       // 128*256*2   = 65,536  -> 265,216
#define OFF_XB   ((size_t)265216)       // 50048*128*2 = 12,812,288 -> 13,077,504
#define OFF_ABB  ((size_t)13077504)     // 50000*768*1 = 38,400,000 -> 51,477,504
#define OFF_AGB  ((size_t)51477504)     // 50048*128*2 = 12,812,288 -> 64,289,792
#define OFF_HIST ((size_t)64289792)     // pad 200,192 -> 64,489,984
#define OFF_EXCL ((size_t)64489984)     // -> 64,690,176
#define OFF_CURS ((size_t)64690176)     // -> 64,890,368
#define OFF_BSUM ((size_t)64890368)     // 256 -> 64,890,624
#define OFF_PACK ((size_t)64890624)     // 600000*4 = 2,400,000

typedef __attribute__((ext_vector_type(8))) short bf16x8;
typedef __attribute__((ext_vector_type(4))) float f32x4;

__device__ inline unsigned short f2bf(float f) {
    union { float f; unsigned u; } c; c.f = f;
    unsigned u = c.u;
    u += 0x7FFF + ((u >> 16) & 1);  // RNE
    return (unsigned short)(u >> 16);
}
__device__ inline float bf2f(unsigned short h) {
    union { unsigned u; float f; } c; c.u = ((unsigned)h) << 16;
    return c.f;
}

// fp8 e4m3fn (OCP) hardware converts; byte-select must be a literal constant
__device__ inline unsigned char f2fp8(float f) {
    int d = __builtin_amdgcn_cvt_pk_fp8_f32(f, f, 0, false);
    return (unsigned char)(d & 0xFF);
}
template <int S>
__device__ inline float fp8f(unsigned q) {
    return __builtin_amdgcn_cvt_f32_fp8(q, S);
}

// ---------------------------------------------------------------------------
// Kernel 0: fused phase-0: weight prep + x->bf16 + dst histogram.
__global__ __launch_bounds__(256) void phase0(const float* __restrict__ Wmsg,
                                              const float* __restrict__ bmsg,
                                              const float* __restrict__ Wupd,
                                              const float* __restrict__ x,
                                              const int* __restrict__ ei,
                                              unsigned short* __restrict__ W6T,
                                              float* __restrict__ Bv,
                                              unsigned short* __restrict__ WuT,
                                              unsigned short* __restrict__ Xb,
                                              int* __restrict__ hist) {
    const int b = blockIdx.x;
    const int tid = threadIdx.x;
    if (b < P0_W6T_END) {
        int idx = b * 256 + tid;
        int col = idx >> 7;
        int k = idx & 127;
        int half = col >= 384;
        int rem = col - half * 384;
        int t = rem >> 7;
        int h = rem & 127;
        W6T[idx] = f2bf(Wmsg[t * 32768 + (half * 128 + k) * 128 + h]);
    } else if (b < P0_BV_END) {
        int idx = (b - P0_W6T_END) * 256 + tid;
        if (idx < 768) Bv[idx] = (idx < 384) ? 0.f : bmsg[idx - 384];
    } else if (b < P0_WUT_END) {
        int idx = (b - P0_BV_END) * 256 + tid;
        int n = idx >> 8;
        int k = idx & 255;
        WuT[idx] = f2bf(Wupd[(size_t)k * 128 + n]);
    } else if (b < P0_XB_END) {
        int i = (b - P0_WUT_END) * 256 + tid;
        int base = i * 4;
        if (base < MPAD * 128) {
            ushort4 o;
            if (base < NNODES * 128) {
                float4 v = *(const float4*)(x + base);
                o.x = f2bf(v.x); o.y = f2bf(v.y); o.z = f2bf(v.z); o.w = f2bf(v.w);
            } else {
                o.x = o.y = o.z = o.w = 0;
            }
            *(ushort4*)(Xb + base) = o;
        }
    } else {
        int e = (b - P0_XB_END) * 256 + tid;
        if (e < NEDGES) atomicAdd(&hist[ei[NEDGES + e]], 1);
    }
}

// ---------------------------------------------------------------------------
// Kernel 2: MFMA GEMM: ABb[50000][768] FP8 = fp8(Xb @ W6T^T + Bv)
__global__ __launch_bounds__(256) void gemm_ab(const unsigned short* __restrict__ Xb,
                                               const unsigned short* __restrict__ W6T,
                                               const float* __restrict__ Bv,
                                               unsigned char* __restrict__ ABb8) {
    __shared__ unsigned char lds_buf[64 * 272];  // 17 KB: xs view (16KB) then fp8 tile
    const int tid = threadIdx.x;
    const int mbase = blockIdx.x * 64;
    const int w = tid >> 6;
    const int nbase = blockIdx.y * 256 + w * 64;
    const int lane = tid & 63;
    const int r = lane & 15;
    const int quad = lane >> 4;

    // Hoisted W6T b-frags (L2-hot, in flight during staging/barriers)
    bf16x8 b[4][4];  // [ks][ni]
#pragma unroll
    for (int ks = 0; ks < 4; ++ks)
#pragma unroll
        for (int ni = 0; ni < 4; ++ni)
            b[ks][ni] = *(const bf16x8*)(W6T + (size_t)(nbase + ni * 16 + r) * 128 + ks * 32 + quad * 8);

    // Stage Xb tile (64 rows x 128 u16) into LDS, swizzled
    unsigned short* xs = (unsigned short*)lds_buf;
#pragma unroll
    for (int i = 0; i < 4; ++i) {
        int item = i * 256 + tid;
        int row = item >> 4;
        int kb = item & 15;
        bf16x8 v = *(const bf16x8*)(Xb + (size_t)(mbase + row) * 128 + kb * 8);
        *(bf16x8*)&xs[row * 128 + ((kb ^ (row & 7)) * 8)] = v;
    }
    __syncthreads();

    f32x4 acc[4][4];
#pragma unroll
    for (int mi = 0; mi < 4; ++mi)
#pragma unroll
        for (int ni = 0; ni < 4; ++ni) acc[mi][ni] = (f32x4){0.f, 0.f, 0.f, 0.f};

#pragma unroll
    for (int ks = 0; ks < 4; ++ks) {
        bf16x8 a[4];
        const int kb = ks * 4 + quad;
#pragma unroll
        for (int mi = 0; mi < 4; ++mi)
            a[mi] = *(const bf16x8*)&xs[(mi * 16 + r) * 128 + ((kb ^ (r & 7)) * 8)];
#pragma unroll
        for (int mi = 0; mi < 4; ++mi)
#pragma unroll
            for (int ni = 0; ni < 4; ++ni)
                acc[mi][ni] = __builtin_amdgcn_mfma_f32_16x16x32_bf16(a[mi], b[ks][ni], acc[mi][ni], 0, 0, 0);
    }

    __syncthreads();  // xs reads done before reusing lds_buf as fp8 tile
    unsigned char (*tile)[272] = (unsigned char(*)[272])lds_buf;

#pragma unroll
    for (int ni = 0; ni < 4; ++ni) {
        const int col_l = w * 64 + ni * 16 + r;
        const float bias = Bv[blockIdx.y * 256 + col_l];
#pragma unroll
        for (int mi = 0; mi < 4; ++mi) {
            f32x4 v = acc[mi][ni];
#pragma unroll
            for (int reg = 0; reg < 4; ++reg) {
                tile[mi * 16 + quad * 4 + reg][col_l] = f2fp8(v[reg] + bias);
            }
        }
    }
    __syncthreads();

    // Coalesced write-out: 64 rows x 256 B per block; 16B/lane-iter.
#pragma unroll
    for (int i = 0; i < 4; ++i) {
        int item = i * 256 + tid;
        int row_l = item >> 4;
        int chunk = item & 15;
        int grow = mbase + row_l;
        if (grow < NNODES) {
            uint4 v = *(const uint4*)&tile[row_l][chunk * 16];
            *(uint4*)(ABb8 + (size_t)grow * 768 + blockIdx.y * 256 + chunk * 16) = v;
        }
    }
}

// ---------------------------------------------------------------------------
// CSR build
__global__ __launch_bounds__(256) void scan_phase1(const int* __restrict__ hist,
                                                   int* __restrict__ excl,
                                                   int* __restrict__ blockSums) {
    __shared__ int lds[256];
    const int blk = blockIdx.x;
    const int t = threadIdx.x;
    const int base = blk * SCAN_CHUNK + t * 4;
    int v[4];
    int s = 0;
#pragma unroll
    for (int i = 0; i < 4; ++i) {
        v[i] = (base + i < NNODES) ? hist[base + i] : 0;
        s += v[i];
    }
    lds[t] = s;
    __syncthreads();
    for (int off = 1; off < 256; off <<= 1) {
        int add = (t >= off) ? lds[t - off] : 0;
        __syncthreads();
        lds[t] += add;
        __syncthreads();
    }
    int incl = lds[t];
    int run = incl - s;
#pragma unroll
    for (int i = 0; i < 4; ++i) {
        if (base + i < NNODES) excl[base + i] = run;
        run += v[i];
    }
    if (t == 255) blockSums[blk] = incl;
}

__global__ __launch_bounds__(256) void scan_phase3(int* __restrict__ excl,
                                                   const int* __restrict__ blockSums,
                                                   int* __restrict__ cursor) {
    __shared__ int s_add;
    const int blk = blockIdx.x;
    const int t = threadIdx.x;
    if (t < 64) {
        int v = (t < blk) ? blockSums[t] : 0;
#pragma unroll
        for (int off = 32; off >= 1; off >>= 1) v += __shfl_xor(v, off, 64);
        if (t == 0) s_add = v;
    }
    __syncthreads();
    const int add = s_add;
    for (int i = t; i < SCAN_CHUNK; i += 256) {
        int idx = blk * SCAN_CHUNK + i;
        if (idx < NNODES) {
            int o = excl[idx] + add;
            excl[idx] = o;
            cursor[idx] = o;
        }
    }
}

// bucket edges by dst; pack dword-offset of fp8 A-row + type:
//   packed = (src*192 + t*32) | (t << 25)
__global__ __launch_bounds__(256) void edge_bucket(const int* __restrict__ ei,
                                                   const int* __restrict__ et,
                                                   int* __restrict__ cursor,
                                                   unsigned* __restrict__ packed) {
    int e = blockIdx.x * 256 + threadIdx.x;
    if (e >= NEDGES) return;
    int src = ei[e];
    int dst = ei[NEDGES + e];
    int t = et[e];
    int pos = atomicAdd(&cursor[dst], 1);
    packed[pos] = (unsigned)(src * 192 + t * 32) | ((unsigned)t << 25);
}

// ---------------------------------------------------------------------------
// Kernel 4: gather aggregation from FP8 table -> normalized bf16 agg.
// One wave per node; paired-edge; 1 dword = 4 fp8 cols per lane per edge.
__global__ __launch_bounds__(256) void aggregate(const unsigned* __restrict__ packed,
                                                 const int* __restrict__ excl,
                                                 const int* __restrict__ hist,
                                                 const unsigned char* __restrict__ ABb8,
                                                 unsigned short* __restrict__ Agb) {
    const int n = blockIdx.x * 4 + (threadIdx.x >> 6);
    const int lane = threadIdx.x & 63;
    if (n >= NNODES) return;
    const int start = excl[n];
    const int deg = hist[n];
    const unsigned* ABu = (const unsigned*)ABb8;

    const int half = lane >> 5;   // which edge of the pair
    const int cl = lane & 31;     // dword index: cols 4*cl .. 4*cl+3

    float s0 = 0.f, s1 = 0.f, s2 = 0.f, s3 = 0.f;
    int c1 = 0, c2 = 0;

    for (int base = 0; base < deg; base += 64) {
        const int m = min(64, deg - base);
        unsigned v = 0;
        if (lane < m) v = packed[start + base + lane];
        int j = 0;
        for (; j + 8 <= m; j += 8) {
            unsigned e0 = __shfl(v, j + 0 + half, 64);
            unsigned e1 = __shfl(v, j + 2 + half, 64);
            unsigned e2 = __shfl(v, j + 4 + half, 64);
            unsigned e3 = __shfl(v, j + 6 + half, 64);
            unsigned q0 = ABu[(e0 & 0x1FFFFFF) + cl];
            unsigned q1 = ABu[(e1 & 0x1FFFFFF) + cl];
            unsigned q2 = ABu[(e2 & 0x1FFFFFF) + cl];
            unsigned q3 = ABu[(e3 & 0x1FFFFFF) + cl];
            int t0 = e0 >> 25, t1 = e1 >> 25, t2 = e2 >> 25, t3 = e3 >> 25;
            c1 += (t0 == 1) + (t1 == 1) + (t2 == 1) + (t3 == 1);
            c2 += (t0 == 2) + (t1 == 2) + (t2 == 2) + (t3 == 2);
            s0 += (fp8f<0>(q0) + fp8f<0>(q1)) + (fp8f<0>(q2) + fp8f<0>(q3));
            s1 += (fp8f<1>(q0) + fp8f<1>(q1)) + (fp8f<1>(q2) + fp8f<1>(q3));
            s2 += (fp8f<2>(q0) + fp8f<2>(q1)) + (fp8f<2>(q2) + fp8f<2>(q3));
            s3 += (fp8f<3>(q0) + fp8f<3>(q1)) + (fp8f<3>(q2) + fp8f<3>(q3));
        }
        for (; j + 2 <= m; j += 2) {
            unsigned e0 = __shfl(v, j + half, 64);
            unsigned q0 = ABu[(e0 & 0x1FFFFFF) + cl];
            int t0 = e0 >> 25;
            c1 += (t0 == 1);
            c2 += (t0 == 2);
            s0 += fp8f<0>(q0); s1 += fp8f<1>(q0);
            s2 += fp8f<2>(q0); s3 += fp8f<3>(q0);
        }
        if (j < m) {  // odd leftover: only half 0 contributes
            unsigned e0 = __shfl(v, j, 64);
            if (half == 0) {
                unsigned q0 = ABu[(e0 & 0x1FFFFFF) + cl];
                int t0 = e0 >> 25;
                c1 += (t0 == 1);
                c2 += (t0 == 2);
                s0 += fp8f<0>(q0); s1 += fp8f<1>(q0);
                s2 += fp8f<2>(q0); s3 += fp8f<3>(q0);
            }
        }
    }

    // combine halves
    s0 += __shfl_xor(s0, 32, 64);
    s1 += __shfl_xor(s1, 32, 64);
    s2 += __shfl_xor(s2, 32, 64);
    s3 += __shfl_xor(s3, 32, 64);
    c1 += __shfl_xor(c1, 32, 64);
    c2 += __shfl_xor(c2, 32, 64);
    const int c0 = deg - c1 - c2;

    // B-half: dword base n*192 + 96, +32 per type
    const unsigned* brow = ABu + (size_t)n * 192 + 96;
    if (c0) {
        unsigned p = brow[cl];
        s0 += c0 * fp8f<0>(p); s1 += c0 * fp8f<1>(p);
        s2 += c0 * fp8f<2>(p); s3 += c0 * fp8f<3>(p);
    }
    if (c1) {
        unsigned p = brow[32 + cl];
        s0 += c1 * fp8f<0>(p); s1 += c1 * fp8f<1>(p);
        s2 += c1 * fp8f<2>(p); s3 += c1 * fp8f<3>(p);
    }
    if (c2) {
        unsigned p = brow[64 + cl];
        s0 += c2 * fp8f<0>(p); s1 += c2 * fp8f<1>(p);
        s2 += c2 * fp8f<2>(p); s3 += c2 * fp8f<3>(p);
    }

    const float inv = 1.0f / fmaxf((float)deg, 1.0f);
    if (half == 0) {
        uint2 o;
        o.x = (unsigned)f2bf(s0 * inv) | ((unsigned)f2bf(s1 * inv) << 16);
        o.y = (unsigned)f2bf(s2 * inv) | ((unsigned)f2bf(s3 * inv) << 16);
        ((uint2*)(Agb + (size_t)n * 128))[cl] = o;
    }
}

// ---------------------------------------------------------------------------
// Kernel 5: persistent MFMA update. Block = 512 thr = 8 waves; wave w owns
// cols [16w,16w+16). B-frags (16 cols x K=256 = 32 VGPR) + bias/gamma/beta
// loaded ONCE, then grid-stride over 16-row tiles (~6 tiles/block). Per tile:
// 8 independent A-loads -> 8 register-only MFMAs (no load in the chain) +
// 1 identity-MFMA residual, LN partials, 1 barrier (sred double-buffered),
// 4-elem epilogue. Grid = 512 = 2 blocks/CU exactly resident.
// (512,4): 128-reg cap, est ~90 used. Spill tripwire: WRITE_SIZE > 30 MB.
__global__ __launch_bounds__(512, 4) void update_mfma(const unsigned short* __restrict__ Xb,
                                                      const unsigned short* __restrict__ Agb,
                                                      const unsigned short* __restrict__ WuT,
                                                      const float* __restrict__ bupd,
                                                      const float* __restrict__ gamma,
                                                      const float* __restrict__ beta,
                                                      float* __restrict__ out) {
    __shared__ float sred[2][8][2][16];  // [buf][wave][s|s2][local row]

    const int tid = threadIdx.x;
    const int w = tid >> 6;        // 0..7: which 16-col slice
    const int lane = tid & 63;
    const int r = lane & 15;
    const int quad = lane >> 4;
    const int col = w * 16 + r;

    // persistent B-frags: WuT[col][k], k = (ks*4+quad)*8 .. +8
    bf16x8 b[8];
#pragma unroll
    for (int ks = 0; ks < 8; ++ks)
        b[ks] = *(const bf16x8*)(WuT + (size_t)col * 256 + (ks * 4 + quad) * 8);

    const float bias = bupd[col];
    const float gg = gamma[col];
    const float bb = beta[col];

    // identity B-frag for residual extraction: target k-row (w&1)*16 + r
    bf16x8 eo;
#pragma unroll
    for (int t = 0; t < 8; ++t)
        eo[t] = (short)((quad * 8 + t == ((w & 1) << 4) + r) ? 0x3F80 : 0);

    int p = 0;
    for (int tile = blockIdx.x; tile < NTILES; tile += gridDim.x, p ^= 1) {
        const int rowbase = tile * 16;

        bf16x8 a[8];
#pragma unroll
        for (int ks = 0; ks < 4; ++ks)
            a[ks] = *(const bf16x8*)(Xb + (size_t)(rowbase + r) * 128 + ks * 32 + quad * 8);
#pragma unroll
        for (int ks = 4; ks < 8; ++ks)
            a[ks] = *(const bf16x8*)(Agb + (size_t)(rowbase + r) * 128 + (ks - 4) * 32 + quad * 8);

        f32x4 acc = (f32x4){0.f, 0.f, 0.f, 0.f};
#pragma unroll
        for (int ks = 0; ks < 8; ++ks)
            acc = __builtin_amdgcn_mfma_f32_16x16x32_bf16(a[ks], b[ks], acc, 0, 0, 0);

        // residual x in C-layout: col in [0,128) -> x-half, source frag a[w>>1]
        f32x4 zz = (f32x4){0.f, 0.f, 0.f, 0.f};
        f32x4 xr = __builtin_amdgcn_mfma_f32_16x16x32_bf16(a[w >> 1], eo, zz, 0, 0, 0);

        float vals[4];
#pragma unroll
        for (int reg = 0; reg < 4; ++reg) vals[reg] = acc[reg] + bias;

        // LN partials over our 16 cols (reduce across r-lanes within quad)
#pragma unroll
        for (int reg = 0; reg < 4; ++reg) {
            float s = vals[reg];
            float s2 = vals[reg] * vals[reg];
#pragma unroll
            for (int off = 8; off >= 1; off >>= 1) {
                s += __shfl_xor(s, off, 64);
                s2 += __shfl_xor(s2, off, 64);
            }
            if (r == 0) {
                sred[p][w][0][quad * 4 + reg] = s;
                sred[p][w][1][quad * 4 + reg] = s2;
            }
        }
        __syncthreads();

#pragma unroll
        for (int reg = 0; reg < 4; ++reg) {
            const int rowL = quad * 4 + reg;
            float s = 0.f, s2 = 0.f;
#pragma unroll
            for (int ww = 0; ww < 8; ++ww) {
                s += sred[p][ww][0][rowL];
                s2 += sred[p][ww][1][rowL];
            }
            const int row = rowbase + rowL;
            if (row < NNODES) {
                const float mu = s * (1.0f / 128.0f);
                const float var = s2 * (1.0f / 128.0f) - mu * mu;
                const float inv = rsqrtf(var + EPS);
                float hn = (vals[reg] - mu) * inv * gg + bb;
                float ge = 0.5f * hn * (1.0f + erff(hn * 0.70710678118654752f));
                out[(size_t)row * 128 + col] = xr[reg] + ge;
            }
        }
    }
}

// ---------------------------------------------------------------------------
extern "C" void kernel_launch(void* const* d_in, const int* in_sizes, int n_in,
                              void* d_out, int out_size, void* d_ws, size_t ws_size,
                              hipStream_t stream) {
    const float* x     = (const float*)d_in[0];
    const int*   ei    = (const int*)d_in[1];
    const int*   et    = (const int*)d_in[2];
    const float* Wmsg  = (const float*)d_in[3];
    const float* bmsg  = (const float*)d_in[4];
    const float* Wupd  = (const float*)d_in[5];
    const float* bupd  = (const float*)d_in[6];
    const float* gamma = (const float*)d_in[7];
    const float* beta  = (const float*)d_in[8];
    float* out = (float*)d_out;

    char* ws = (char*)d_ws;
    unsigned short* W6T  = (unsigned short*)(ws + OFF_W6T);
    float*          Bv   = (float*)(ws + OFF_BV);
    unsigned short* WuT  = (unsigned short*)(ws + OFF_WUT);
    unsigned short* Xb   = (unsigned short*)(ws + OFF_XB);
    unsigned char*  ABb8 = (unsigned char*)(ws + OFF_ABB);
    unsigned short* Agb  = (unsigned short*)(ws + OFF_AGB);
    int*            hist = (int*)(ws + OFF_HIST);
    int*            excl = (int*)(ws + OFF_EXCL);
    int*            curs = (int*)(ws + OFF_CURS);
    int*            bsum = (int*)(ws + OFF_BSUM);
    unsigned*       pack = (unsigned*)(ws + OFF_PACK);

    (void)hipMemsetAsync(hist, 0, NNODES * sizeof(int), stream);

    phase0<<<P0_HIST_END, 256, 0, stream>>>(Wmsg, bmsg, Wupd, x, ei, W6T, Bv, WuT, Xb, hist);
    gemm_ab<<<dim3(MPAD / 64, 3), 256, 0, stream>>>(Xb, W6T, Bv, ABb8);
    scan_phase1<<<NSCAN_BLOCKS, 256, 0, stream>>>(hist, excl, bsum);
    scan_phase3<<<NSCAN_BLOCKS, 256, 0, stream>>>(excl, bsum, curs);
    edge_bucket<<<(NEDGES + 255) / 256, 256, 0, stream>>>(ei, et, curs, pack);
    aggregate<<<(NNODES + 3) / 4, 256, 0, stream>>>(pack, excl, hist, ABb8, Agb);
    update_mfma<<<512, 512, 0, stream>>>(Xb, Agb, WuT, bupd, gamma, beta, out);
}

// Round 7
// 253.158 us; speedup vs baseline: 1.1673x; 1.1673x over previous
//
#include <hip/hip_runtime.h>
#include <hip/hip_bf16.h>
#include <math.h>

#define HIDDEN 128
#define NNODES 50000
#define NEDGES 600000
#define EPS 1e-5f
#define SCAN_CHUNK 1024
#define NSCAN_BLOCKS ((NNODES + SCAN_CHUNK - 1) / SCAN_CHUNK)  // 49
#define MPAD 50048  // 782 * 64

// phase0 block ranges
#define P0_W6T_END   384
#define P0_BV_END    387
#define P0_WUT_END   515
#define P0_XB_END    (515 + 6256)            // MPAD*128/4/256 = 6256 blocks
#define P0_HIST_END  (P0_XB_END + 2344)      // (NEDGES+255)/256 = 2344 blocks

// Workspace layout (bytes), all 16B-aligned. ABb is FP8 (1B/elem).
#define OFF_W6T  ((size_t)0)            // 768*128*2   = 196,608
#define OFF_BV   ((size_t)196608)       // 768*4       = 3,072   -> 199,680
#define OFF_WUT  ((size_t)199680)       // 128*256*2   = 65,536  -> 265,216
#define OFF_XB   ((size_t)265216)       // 50048*128*2 = 12,812,288 -> 13,077,504
#define OFF_ABB  ((size_t)13077504)     // 50000*768*1 = 38,400,000 -> 51,477,504
#define OFF_AGB  ((size_t)51477504)     // 50048*128*2 = 12,812,288 -> 64,289,792
#define OFF_HIST ((size_t)64289792)     // pad 200,192 -> 64,489,984
#define OFF_EXCL ((size_t)64489984)     // -> 64,690,176
#define OFF_CURS ((size_t)64690176)     // -> 64,890,368
#define OFF_BSUM ((size_t)64890368)     // 256 -> 64,890,624
#define OFF_PACK ((size_t)64890624)     // 600000*4 = 2,400,000

typedef __attribute__((ext_vector_type(8))) short bf16x8;
typedef __attribute__((ext_vector_type(4))) float f32x4;

__device__ inline unsigned short f2bf(float f) {
    union { float f; unsigned u; } c; c.f = f;
    unsigned u = c.u;
    u += 0x7FFF + ((u >> 16) & 1);  // RNE
    return (unsigned short)(u >> 16);
}
__device__ inline float bf2f(unsigned short h) {
    union { unsigned u; float f; } c; c.u = ((unsigned)h) << 16;
    return c.f;
}

// fp8 e4m3fn (OCP) hardware converts; byte-select must be a literal constant
__device__ inline unsigned char f2fp8(float f) {
    int d = __builtin_amdgcn_cvt_pk_fp8_f32(f, f, 0, false);
    return (unsigned char)(d & 0xFF);
}
template <int S>
__device__ inline float fp8f(unsigned q) {
    return __builtin_amdgcn_cvt_f32_fp8(q, S);
}

// Exact-GELU via Abramowitz-Stegun 7.1.26 erf (max err 1.5e-7): ~15 VALU inst
// vs libm erff's ~100+. 6.4M calls/dispatch made erff the dominant VALU cost
// (R5/R6: VALUBusy 62-64% invariant across partitionings).
__device__ inline float gelu_fast(float h) {
    float ar = h * 0.70710678118654752f;
    float aa = fabsf(ar);
    float t = __builtin_amdgcn_rcpf(fmaf(0.3275911f, aa, 1.0f));
    float p = t * fmaf(t, fmaf(t, fmaf(t, fmaf(t, 1.061405429f,
                                               -1.453152027f),
                                       1.421413741f),
                               -0.284496736f),
                       0.254829592f);
    float ex = __expf(-aa * aa);
    float er = copysignf(1.0f - p * ex, ar);
    return 0.5f * h * (1.0f + er);
}

// ---------------------------------------------------------------------------
// Kernel 0: fused phase-0: weight prep + x->bf16 + dst histogram.
__global__ __launch_bounds__(256) void phase0(const float* __restrict__ Wmsg,
                                              const float* __restrict__ bmsg,
                                              const float* __restrict__ Wupd,
                                              const float* __restrict__ x,
                                              const int* __restrict__ ei,
                                              unsigned short* __restrict__ W6T,
                                              float* __restrict__ Bv,
                                              unsigned short* __restrict__ WuT,
                                              unsigned short* __restrict__ Xb,
                                              int* __restrict__ hist) {
    const int b = blockIdx.x;
    const int tid = threadIdx.x;
    if (b < P0_W6T_END) {
        int idx = b * 256 + tid;
        int col = idx >> 7;
        int k = idx & 127;
        int half = col >= 384;
        int rem = col - half * 384;
        int t = rem >> 7;
        int h = rem & 127;
        W6T[idx] = f2bf(Wmsg[t * 32768 + (half * 128 + k) * 128 + h]);
    } else if (b < P0_BV_END) {
        int idx = (b - P0_W6T_END) * 256 + tid;
        if (idx < 768) Bv[idx] = (idx < 384) ? 0.f : bmsg[idx - 384];
    } else if (b < P0_WUT_END) {
        int idx = (b - P0_BV_END) * 256 + tid;
        int n = idx >> 8;
        int k = idx & 255;
        WuT[idx] = f2bf(Wupd[(size_t)k * 128 + n]);
    } else if (b < P0_XB_END) {
        int i = (b - P0_WUT_END) * 256 + tid;
        int base = i * 4;
        if (base < MPAD * 128) {
            ushort4 o;
            if (base < NNODES * 128) {
                float4 v = *(const float4*)(x + base);
                o.x = f2bf(v.x); o.y = f2bf(v.y); o.z = f2bf(v.z); o.w = f2bf(v.w);
            } else {
                o.x = o.y = o.z = o.w = 0;
            }
            *(ushort4*)(Xb + base) = o;
        }
    } else {
        int e = (b - P0_XB_END) * 256 + tid;
        if (e < NEDGES) atomicAdd(&hist[ei[NEDGES + e]], 1);
    }
}

// ---------------------------------------------------------------------------
// Kernel 2: MFMA GEMM: ABb[50000][768] FP8 = fp8(Xb @ W6T^T + Bv)
__global__ __launch_bounds__(256) void gemm_ab(const unsigned short* __restrict__ Xb,
                                               const unsigned short* __restrict__ W6T,
                                               const float* __restrict__ Bv,
                                               unsigned char* __restrict__ ABb8) {
    __shared__ unsigned char lds_buf[64 * 272];  // 17 KB: xs view (16KB) then fp8 tile
    const int tid = threadIdx.x;
    const int mbase = blockIdx.x * 64;
    const int w = tid >> 6;
    const int nbase = blockIdx.y * 256 + w * 64;
    const int lane = tid & 63;
    const int r = lane & 15;
    const int quad = lane >> 4;

    // Hoisted W6T b-frags (L2-hot, in flight during staging/barriers)
    bf16x8 b[4][4];  // [ks][ni]
#pragma unroll
    for (int ks = 0; ks < 4; ++ks)
#pragma unroll
        for (int ni = 0; ni < 4; ++ni)
            b[ks][ni] = *(const bf16x8*)(W6T + (size_t)(nbase + ni * 16 + r) * 128 + ks * 32 + quad * 8);

    // Stage Xb tile (64 rows x 128 u16) into LDS, swizzled
    unsigned short* xs = (unsigned short*)lds_buf;
#pragma unroll
    for (int i = 0; i < 4; ++i) {
        int item = i * 256 + tid;
        int row = item >> 4;
        int kb = item & 15;
        bf16x8 v = *(const bf16x8*)(Xb + (size_t)(mbase + row) * 128 + kb * 8);
        *(bf16x8*)&xs[row * 128 + ((kb ^ (row & 7)) * 8)] = v;
    }
    __syncthreads();

    f32x4 acc[4][4];
#pragma unroll
    for (int mi = 0; mi < 4; ++mi)
#pragma unroll
        for (int ni = 0; ni < 4; ++ni) acc[mi][ni] = (f32x4){0.f, 0.f, 0.f, 0.f};

#pragma unroll
    for (int ks = 0; ks < 4; ++ks) {
        bf16x8 a[4];
        const int kb = ks * 4 + quad;
#pragma unroll
        for (int mi = 0; mi < 4; ++mi)
            a[mi] = *(const bf16x8*)&xs[(mi * 16 + r) * 128 + ((kb ^ (r & 7)) * 8)];
#pragma unroll
        for (int mi = 0; mi < 4; ++mi)
#pragma unroll
            for (int ni = 0; ni < 4; ++ni)
                acc[mi][ni] = __builtin_amdgcn_mfma_f32_16x16x32_bf16(a[mi], b[ks][ni], acc[mi][ni], 0, 0, 0);
    }

    __syncthreads();  // xs reads done before reusing lds_buf as fp8 tile
    unsigned char (*tile)[272] = (unsigned char(*)[272])lds_buf;

#pragma unroll
    for (int ni = 0; ni < 4; ++ni) {
        const int col_l = w * 64 + ni * 16 + r;
        const float bias = Bv[blockIdx.y * 256 + col_l];
#pragma unroll
        for (int mi = 0; mi < 4; ++mi) {
            f32x4 v = acc[mi][ni];
#pragma unroll
            for (int reg = 0; reg < 4; ++reg) {
                tile[mi * 16 + quad * 4 + reg][col_l] = f2fp8(v[reg] + bias);
            }
        }
    }
    __syncthreads();

    // Coalesced write-out: 64 rows x 256 B per block; 16B/lane-iter.
#pragma unroll
    for (int i = 0; i < 4; ++i) {
        int item = i * 256 + tid;
        int row_l = item >> 4;
        int chunk = item & 15;
        int grow = mbase + row_l;
        if (grow < NNODES) {
            uint4 v = *(const uint4*)&tile[row_l][chunk * 16];
            *(uint4*)(ABb8 + (size_t)grow * 768 + blockIdx.y * 256 + chunk * 16) = v;
        }
    }
}

// ---------------------------------------------------------------------------
// CSR build
__global__ __launch_bounds__(256) void scan_phase1(const int* __restrict__ hist,
                                                   int* __restrict__ excl,
                                                   int* __restrict__ blockSums) {
    __shared__ int lds[256];
    const int blk = blockIdx.x;
    const int t = threadIdx.x;
    const int base = blk * SCAN_CHUNK + t * 4;
    int v[4];
    int s = 0;
#pragma unroll
    for (int i = 0; i < 4; ++i) {
        v[i] = (base + i < NNODES) ? hist[base + i] : 0;
        s += v[i];
    }
    lds[t] = s;
    __syncthreads();
    for (int off = 1; off < 256; off <<= 1) {
        int add = (t >= off) ? lds[t - off] : 0;
        __syncthreads();
        lds[t] += add;
        __syncthreads();
    }
    int incl = lds[t];
    int run = incl - s;
#pragma unroll
    for (int i = 0; i < 4; ++i) {
        if (base + i < NNODES) excl[base + i] = run;
        run += v[i];
    }
    if (t == 255) blockSums[blk] = incl;
}

__global__ __launch_bounds__(256) void scan_phase3(int* __restrict__ excl,
                                                   const int* __restrict__ blockSums,
                                                   int* __restrict__ cursor) {
    __shared__ int s_add;
    const int blk = blockIdx.x;
    const int t = threadIdx.x;
    if (t < 64) {
        int v = (t < blk) ? blockSums[t] : 0;
#pragma unroll
        for (int off = 32; off >= 1; off >>= 1) v += __shfl_xor(v, off, 64);
        if (t == 0) s_add = v;
    }
    __syncthreads();
    const int add = s_add;
    for (int i = t; i < SCAN_CHUNK; i += 256) {
        int idx = blk * SCAN_CHUNK + i;
        if (idx < NNODES) {
            int o = excl[idx] + add;
            excl[idx] = o;
            cursor[idx] = o;
        }
    }
}

// bucket edges by dst; pack dword-offset of fp8 A-row + type:
//   packed = (src*192 + t*32) | (t << 25)
__global__ __launch_bounds__(256) void edge_bucket(const int* __restrict__ ei,
                                                   const int* __restrict__ et,
                                                   int* __restrict__ cursor,
                                                   unsigned* __restrict__ packed) {
    int e = blockIdx.x * 256 + threadIdx.x;
    if (e >= NEDGES) return;
    int src = ei[e];
    int dst = ei[NEDGES + e];
    int t = et[e];
    int pos = atomicAdd(&cursor[dst], 1);
    packed[pos] = (unsigned)(src * 192 + t * 32) | ((unsigned)t << 25);
}

// ---------------------------------------------------------------------------
// Kernel 4: gather aggregation from FP8 table -> normalized bf16 agg.
// One wave per node; paired-edge; 1 dword = 4 fp8 cols per lane per edge.
__global__ __launch_bounds__(256) void aggregate(const unsigned* __restrict__ packed,
                                                 const int* __restrict__ excl,
                                                 const int* __restrict__ hist,
                                                 const unsigned char* __restrict__ ABb8,
                                                 unsigned short* __restrict__ Agb) {
    const int n = blockIdx.x * 4 + (threadIdx.x >> 6);
    const int lane = threadIdx.x & 63;
    if (n >= NNODES) return;
    const int start = excl[n];
    const int deg = hist[n];
    const unsigned* ABu = (const unsigned*)ABb8;

    const int half = lane >> 5;   // which edge of the pair
    const int cl = lane & 31;     // dword index: cols 4*cl .. 4*cl+3

    float s0 = 0.f, s1 = 0.f, s2 = 0.f, s3 = 0.f;
    int c1 = 0, c2 = 0;

    for (int base = 0; base < deg; base += 64) {
        const int m = min(64, deg - base);
        unsigned v = 0;
        if (lane < m) v = packed[start + base + lane];
        int j = 0;
        for (; j + 8 <= m; j += 8) {
            unsigned e0 = __shfl(v, j + 0 + half, 64);
            unsigned e1 = __shfl(v, j + 2 + half, 64);
            unsigned e2 = __shfl(v, j + 4 + half, 64);
            unsigned e3 = __shfl(v, j + 6 + half, 64);
            unsigned q0 = ABu[(e0 & 0x1FFFFFF) + cl];
            unsigned q1 = ABu[(e1 & 0x1FFFFFF) + cl];
            unsigned q2 = ABu[(e2 & 0x1FFFFFF) + cl];
            unsigned q3 = ABu[(e3 & 0x1FFFFFF) + cl];
            int t0 = e0 >> 25, t1 = e1 >> 25, t2 = e2 >> 25, t3 = e3 >> 25;
            c1 += (t0 == 1) + (t1 == 1) + (t2 == 1) + (t3 == 1);
            c2 += (t0 == 2) + (t1 == 2) + (t2 == 2) + (t3 == 2);
            s0 += (fp8f<0>(q0) + fp8f<0>(q1)) + (fp8f<0>(q2) + fp8f<0>(q3));
            s1 += (fp8f<1>(q0) + fp8f<1>(q1)) + (fp8f<1>(q2) + fp8f<1>(q3));
            s2 += (fp8f<2>(q0) + fp8f<2>(q1)) + (fp8f<2>(q2) + fp8f<2>(q3));
            s3 += (fp8f<3>(q0) + fp8f<3>(q1)) + (fp8f<3>(q2) + fp8f<3>(q3));
        }
        for (; j + 2 <= m; j += 2) {
            unsigned e0 = __shfl(v, j + half, 64);
            unsigned q0 = ABu[(e0 & 0x1FFFFFF) + cl];
            int t0 = e0 >> 25;
            c1 += (t0 == 1);
            c2 += (t0 == 2);
            s0 += fp8f<0>(q0); s1 += fp8f<1>(q0);
            s2 += fp8f<2>(q0); s3 += fp8f<3>(q0);
        }
        if (j < m) {  // odd leftover: only half 0 contributes
            unsigned e0 = __shfl(v, j, 64);
            if (half == 0) {
                unsigned q0 = ABu[(e0 & 0x1FFFFFF) + cl];
                int t0 = e0 >> 25;
                c1 += (t0 == 1);
                c2 += (t0 == 2);
                s0 += fp8f<0>(q0); s1 += fp8f<1>(q0);
                s2 += fp8f<2>(q0); s3 += fp8f<3>(q0);
            }
        }
    }

    // combine halves
    s0 += __shfl_xor(s0, 32, 64);
    s1 += __shfl_xor(s1, 32, 64);
    s2 += __shfl_xor(s2, 32, 64);
    s3 += __shfl_xor(s3, 32, 64);
    c1 += __shfl_xor(c1, 32, 64);
    c2 += __shfl_xor(c2, 32, 64);
    const int c0 = deg - c1 - c2;

    // B-half: dword base n*192 + 96, +32 per type
    const unsigned* brow = ABu + (size_t)n * 192 + 96;
    if (c0) {
        unsigned p = brow[cl];
        s0 += c0 * fp8f<0>(p); s1 += c0 * fp8f<1>(p);
        s2 += c0 * fp8f<2>(p); s3 += c0 * fp8f<3>(p);
    }
    if (c1) {
        unsigned p = brow[32 + cl];
        s0 += c1 * fp8f<0>(p); s1 += c1 * fp8f<1>(p);
        s2 += c1 * fp8f<2>(p); s3 += c1 * fp8f<3>(p);
    }
    if (c2) {
        unsigned p = brow[64 + cl];
        s0 += c2 * fp8f<0>(p); s1 += c2 * fp8f<1>(p);
        s2 += c2 * fp8f<2>(p); s3 += c2 * fp8f<3>(p);
    }

    const float inv = 1.0f / fmaxf((float)deg, 1.0f);
    if (half == 0) {
        uint2 o;
        o.x = (unsigned)f2bf(s0 * inv) | ((unsigned)f2bf(s1 * inv) << 16);
        o.y = (unsigned)f2bf(s2 * inv) | ((unsigned)f2bf(s3 * inv) << 16);
        ((uint2*)(Agb + (size_t)n * 128))[cl] = o;
    }
}

// ---------------------------------------------------------------------------
// Kernel 5: MFMA update, col-split (R3 structure, best measured: 42.0 µs).
// Block = 32 rows; 4 waves = 2 row-tiles x 2 col-halves. Per wave: 8 A-frag +
// 32 B-frag loads (WuT from L2), 32 MFMAs, 16 LN/GELU elems/thread. LN stats
// combined across col-half waves via 512 B LDS + 1 barrier. Residual read
// from fp32 x (prefetched before the barrier). GELU via A&S fast-erf.
// (256,4): 128-reg cap. Empirical: (256,5)=102-reg cap spills ~125 B/thread
// (R2/R4); (256,4) allocates clean (R3: VGPR=40). Do not tighten.
__global__ __launch_bounds__(256, 4) void update_mfma(const unsigned short* __restrict__ Xb,
                                                      const unsigned short* __restrict__ Agb,
                                                      const unsigned short* __restrict__ WuT,
                                                      const float* __restrict__ bupd,
                                                      const float* __restrict__ gamma,
                                                      const float* __restrict__ beta,
                                                      const float* __restrict__ x,
                                                      float* __restrict__ out) {
    __shared__ float sred[2][2][32];  // [colhalf][s|s2][local row 0..31]

    const int tid = threadIdx.x;
    const int w = tid >> 6;
    const int wrow = w >> 1;      // 0..1: which 16-row tile
    const int whalf = w & 1;      // 0..1: which 64-col half
    const int lane = tid & 63;
    const int r = lane & 15;
    const int quad = lane >> 4;
    const int rowbase = blockIdx.x * 32 + wrow * 16;
    const int nibase = whalf * 4;

    bf16x8 a[8];
#pragma unroll
    for (int ks = 0; ks < 4; ++ks)
        a[ks] = *(const bf16x8*)(Xb + (size_t)(rowbase + r) * 128 + ks * 32 + quad * 8);
#pragma unroll
    for (int ks = 4; ks < 8; ++ks)
        a[ks] = *(const bf16x8*)(Agb + (size_t)(rowbase + r) * 128 + (ks - 4) * 32 + quad * 8);

    f32x4 acc[4];
#pragma unroll
    for (int nl = 0; nl < 4; ++nl) acc[nl] = (f32x4){0.f, 0.f, 0.f, 0.f};

#pragma unroll
    for (int ks = 0; ks < 8; ++ks) {
        const int kb = ks * 4 + quad;
#pragma unroll
        for (int nl = 0; nl < 4; ++nl) {
            bf16x8 b = *(const bf16x8*)(WuT + (size_t)((nibase + nl) * 16 + r) * 256 + kb * 8);
            acc[nl] = __builtin_amdgcn_mfma_f32_16x16x32_bf16(a[ks], b, acc[nl], 0, 0, 0);
        }
    }

    float vals[4][4];
    float gcol[4], bcol[4];
#pragma unroll
    for (int nl = 0; nl < 4; ++nl) {
        const int col = (nibase + nl) * 16 + r;
        const float bias = bupd[col];
        gcol[nl] = gamma[col];
        bcol[nl] = beta[col];
#pragma unroll
        for (int reg = 0; reg < 4; ++reg) vals[nl][reg] = acc[nl][reg] + bias;
    }

    // prefetch residual x (fp32) — latency hides under reduction + barrier
    float xres[4][4];  // [reg][nl]
#pragma unroll
    for (int reg = 0; reg < 4; ++reg) {
        const int row = rowbase + quad * 4 + reg;
#pragma unroll
        for (int nl = 0; nl < 4; ++nl) {
            const int col = (nibase + nl) * 16 + r;
            xres[reg][nl] = (row < NNODES) ? x[(size_t)row * 128 + col] : 0.f;
        }
    }

    // partial LN stats over our 64 cols, per output row
#pragma unroll
    for (int reg = 0; reg < 4; ++reg) {
        float s = 0.f, s2 = 0.f;
#pragma unroll
        for (int nl = 0; nl < 4; ++nl) {
            s += vals[nl][reg];
            s2 += vals[nl][reg] * vals[nl][reg];
        }
#pragma unroll
        for (int off = 8; off >= 1; off >>= 1) {
            s += __shfl_xor(s, off, 64);
            s2 += __shfl_xor(s2, off, 64);
        }
        if (r == 0) {
            const int rowL = wrow * 16 + quad * 4 + reg;
            sred[whalf][0][rowL] = s;
            sred[whalf][1][rowL] = s2;
        }
    }
    __syncthreads();

#pragma unroll
    for (int reg = 0; reg < 4; ++reg) {
        const int rowL = wrow * 16 + quad * 4 + reg;
        const float s = sred[0][0][rowL] + sred[1][0][rowL];
        const float s2 = sred[0][1][rowL] + sred[1][1][rowL];
        const int row = rowbase + quad * 4 + reg;
        if (row < NNODES) {
            const float mu = s * (1.0f / 128.0f);
            const float var = s2 * (1.0f / 128.0f) - mu * mu;
            const float inv = rsqrtf(var + EPS);
#pragma unroll
            for (int nl = 0; nl < 4; ++nl) {
                const int col = (nibase + nl) * 16 + r;
                float hn = (vals[nl][reg] - mu) * inv * gcol[nl] + bcol[nl];
                out[(size_t)row * 128 + col] = xres[reg][nl] + gelu_fast(hn);
            }
        }
    }
}

// ---------------------------------------------------------------------------
extern "C" void kernel_launch(void* const* d_in, const int* in_sizes, int n_in,
                              void* d_out, int out_size, void* d_ws, size_t ws_size,
                              hipStream_t stream) {
    const float* x     = (const float*)d_in[0];
    const int*   ei    = (const int*)d_in[1];
    const int*   et    = (const int*)d_in[2];
    const float* Wmsg  = (const float*)d_in[3];
    const float* bmsg  = (const float*)d_in[4];
    const float* Wupd  = (const float*)d_in[5];
    const float* bupd  = (const float*)d_in[6];
    const float* gamma = (const float*)d_in[7];
    const float* beta  = (const float*)d_in[8];
    float* out = (float*)d_out;

    char* ws = (char*)d_ws;
    unsigned short* W6T  = (unsigned short*)(ws + OFF_W6T);
    float*          Bv   = (float*)(ws + OFF_BV);
    unsigned short* WuT  = (unsigned short*)(ws + OFF_WUT);
    unsigned short* Xb   = (unsigned short*)(ws + OFF_XB);
    unsigned char*  ABb8 = (unsigned char*)(ws + OFF_ABB);
    unsigned short* Agb  = (unsigned short*)(ws + OFF_AGB);
    int*            hist = (int*)(ws + OFF_HIST);
    int*            excl = (int*)(ws + OFF_EXCL);
    int*            curs = (int*)(ws + OFF_CURS);
    int*            bsum = (int*)(ws + OFF_BSUM);
    unsigned*       pack = (unsigned*)(ws + OFF_PACK);

    (void)hipMemsetAsync(hist, 0, NNODES * sizeof(int), stream);

    phase0<<<P0_HIST_END, 256, 0, stream>>>(Wmsg, bmsg, Wupd, x, ei, W6T, Bv, WuT, Xb, hist);
    gemm_ab<<<dim3(MPAD / 64, 3), 256, 0, stream>>>(Xb, W6T, Bv, ABb8);
    scan_phase1<<<NSCAN_BLOCKS, 256, 0, stream>>>(hist, excl, bsum);
    scan_phase3<<<NSCAN_BLOCKS, 256, 0, stream>>>(excl, bsum, curs);
    edge_bucket<<<(NEDGES + 255) / 256, 256, 0, stream>>>(ei, et, curs, pack);
    aggregate<<<(NNODES + 3) / 4, 256, 0, stream>>>(pack, excl, hist, ABb8, Agb);
    update_mfma<<<MPAD / 32, 256, 0, stream>>>(Xb, Agb, WuT, bupd, gamma, beta, x, out);
}